// Round 1
// baseline (4067.100 us; speedup 1.0000x reference)
//
#include <hip/hip_runtime.h>

// ROSA 1-bit layer: suffix-automaton next-symbol predictor.
// B=2, T=2048, C=128. 256 independent sequences, one workgroup (1 wave) each.
// Automaton lives in LDS as packed int16 fields; lane 0 runs the sequential
// construction (faithful port of the reference), all lanes do load/store.

#define B_   2
#define T_   2048
#define C_   128
#define MAXS 4100   // max states = 2T+1 = 4097, padded

typedef unsigned int       u32;
typedef unsigned short     u16;
typedef unsigned long long u64;

__global__ __launch_bounds__(64)
void rosa_kernel(const float* __restrict__ x,
                 const float* __restrict__ emb0,
                 const float* __restrict__ emb1,
                 float* __restrict__ out)
{
    // transitions: lo16 = next state for symbol 0, hi16 = symbol 1; 0xFFFF = none
    __shared__ u32  tr[MAXS];
    // lo16 = suffix link (signed), hi16 = e (last end pos, signed); one read = both
    __shared__ u32  le[MAXS];
    __shared__ short len_[MAXS];
    __shared__ u64  bits[T_ / 64];
    __shared__ signed char y8[T_];

    const int blk  = blockIdx.x;
    const int b    = blk / C_;
    const int c    = blk % C_;
    const int lane = threadIdx.x;

    // ---- phase 1: cooperative bit packing (64 lanes, ballot) ----
    const float* xp = x + (size_t)b * T_ * C_ + c;
    for (int k = 0; k < T_ / 64; ++k) {
        float v = xp[(size_t)(k * 64 + lane) * C_];
        u64 m = __ballot(v > 0.0f);
        if (lane == 0) bits[k] = m;
    }
    __syncthreads();

    // ---- phase 2: sequential suffix-automaton (lane 0 only) ----
    if (lane == 0) {
        u16*   tr16 = (u16*)tr;
        short* le16 = (short*)le;

        tr[0]   = 0xFFFFFFFFu;   // no transitions
        le[0]   = 0xFFFFFFFFu;   // link = -1, e = -1
        len_[0] = 0;

        int g = 0, z = 1;
        for (int i = 0; i < T_; ++i) {
            const int t = (int)((bits[i >> 6] >> (i & 63)) & 1ull);
            const int sh = t << 4;

            const int r = z++;
            tr[r]   = 0xFFFFFFFFu;
            len_[r] = (short)(len_[g] + 1);

            int p = g;
            int q = -1;
            while (p != -1) {
                u32 trp = tr[p];           // both reads independent -> issued together
                u32 lep = le[p];
                u32 nxt = (trp >> sh) & 0xFFFFu;
                if (nxt != 0xFFFFu) { q = (int)nxt; break; }
                tr16[2 * p + t] = (u16)r;  // b[p][t] = r
                p = (short)(lep & 0xFFFFu);
            }

            int linkr;
            if (p == -1) {
                linkr = 0;
            } else if ((int)len_[p] + 1 == (int)len_[q]) {
                linkr = q;
            } else {
                const int u = z++;
                tr[u]   = tr[q];                       // b[u] = b[q].copy()
                len_[u] = (short)(len_[p] + 1);
                le[u]   = le[q];                       // c[u]=c[q], e[u]=e[q]
                while (p != -1) {
                    u32 trp = tr[p];
                    u32 lep = le[p];
                    if (((trp >> sh) & 0xFFFFu) != (u32)q) break;
                    tr16[2 * p + t] = (u16)u;          // b[p][t] = u
                    p = (short)(lep & 0xFFFFu);
                }
                le16[2 * q] = (short)u;                // c[q] = u
                linkr = u;
            }
            le[r] = 0xFFFF0000u | (u16)linkr;          // e[r] = -1, c[r] = linkr
            g = r;

            // predictor: first v on suffix chain with d[v]>0 (== v!=0) and e[v]>=0
            int a = -1;
            int v = g;
            while (v != -1) {
                if (v != 0) {
                    u32 lev = le[v];
                    short ev = (short)(lev >> 16);
                    if (ev >= 0) {
                        int j = ev + 1;
                        a = (int)((bits[j >> 6] >> (j & 63)) & 1ull);
                        break;
                    }
                    v = (short)(lev & 0xFFFFu);
                } else {
                    v = (short)(le[0] & 0xFFFFu);      // c[0] == -1
                }
            }
            y8[i] = (signed char)a;

            // e-update walk: set e[v] = i along the whole suffix chain
            v = g;
            while (v != -1) {
                u32 lev = le[v];
                short ev = (short)(lev >> 16);
                if (ev >= i) break;                    // faithful guard
                le16[2 * v + 1] = (short)i;
                v = (short)(lev & 0xFFFFu);
            }
        }
    }
    __syncthreads();

    // ---- phase 3: select + store (all 64 lanes) ----
    const float e0 = emb0[c];
    const float e1 = emb1[c];
    float* op = out + (size_t)b * T_ * C_ + c;
    for (int tt = lane; tt < T_; tt += 64) {
        int yv = y8[tt];
        float val = (yv < 0) ? 0.0f : (yv ? e1 : e0);
        op[(size_t)tt * C_] = val;
    }
}

extern "C" void kernel_launch(void* const* d_in, const int* in_sizes, int n_in,
                              void* d_out, int out_size, void* d_ws, size_t ws_size,
                              hipStream_t stream)
{
    const float* x    = (const float*)d_in[0];
    const float* emb0 = (const float*)d_in[1];
    const float* emb1 = (const float*)d_in[2];
    float* out = (float*)d_out;

    dim3 grid(B_ * C_);
    dim3 block(64);
    rosa_kernel<<<grid, block, 0, stream>>>(x, emb0, emb1, out);
}

// Round 2
// 1275.448 us; speedup vs baseline: 3.1888x; 3.1888x over previous
//
#include <hip/hip_runtime.h>

// ROSA 1-bit layer — wave-parallel suffix automaton.
// The suffix-link chain of the last state is kept EXPLICITLY, one state per
// lane (vch). All reference walks (transition-set, clone-redirect, predictor,
// e-update) become wave-wide LDS gathers + ballots instead of dependent
// pointer chases. The suffix-link array c[] is never materialized: the new
// chain is [r] + dedupe_adjacent(images of old chain from k) + [root].

#define B_   2
#define T_   2048
#define C_   128
#define MAXS 4100   // max states = 2T+1 = 4097

typedef unsigned int       u32;
typedef unsigned short     u16;
typedef unsigned long long u64;
typedef u16 __attribute__((may_alias)) u16a;   // half-word LDS access w/o TBAA reorder

__global__ __launch_bounds__(64)
void rosa_kernel(const float* __restrict__ x,
                 const float* __restrict__ emb0,
                 const float* __restrict__ emb1,
                 float* __restrict__ out)
{
    // tr[v]: lo16 = transition on 0, hi16 = transition on 1; 0xFFFF = none
    __shared__ u32 tr[MAXS];
    // el[v]: lo16 = e (last end pos, s16, -1 = unset), hi16 = len
    __shared__ u32 el[MAXS];
    __shared__ u64 bits[T_ / 64];
    __shared__ signed char y8[T_];

    const int blk  = blockIdx.x;
    const int bb   = blk >> 7;          // / C_
    const int cc   = blk & (C_ - 1);    // % C_
    const int lane = threadIdx.x;

    // ---- phase 1: cooperative bit packing ----
    const float* xp = x + (size_t)bb * T_ * C_ + cc;
    for (int k = 0; k < T_ / 64; ++k) {
        float v = xp[(size_t)(k * 64 + lane) * C_];
        u64 m = __ballot(v > 0.0f);
        if (lane == 0) bits[k] = m;
    }
    __syncthreads();

    u16a* tr16 = (u16a*)tr;
    u16a* el16 = (u16a*)el;

    if (lane == 0) { tr[0] = 0xFFFFFFFFu; el[0] = 0x0000FFFFu; }  // root: len 0, e=-1
    __syncthreads();

    // ---- phase 2: wave-parallel construction ----
    int vch = 0;     // lane j holds chain state j (top = last state g, bottom = root)
    int L   = 1;     // chain length
    int z   = 1;     // next free state id
    u64 curw = bits[0];
    u64 nxtw = 0;

    for (int i = 0; i < T_; ++i) {
        if ((i & 63) == 0) {
            int w = (i >> 6) + 1;
            nxtw = (w < T_ / 64) ? bits[w] : 0ull;   // prefetch, used 64 steps later
        }
        const int t  = (int)((curw >> (i & 63)) & 1ull);
        const int sh = t << 4;
        const int r  = z++;

        // ---- round A: gather tr/el of all chain states ----
        const bool act = lane < L;
        const u32 trv = tr[vch];
        const u32 elv = el[vch];
        const int qj  = (int)((trv >> sh) & 0xFFFFu);

        const u64 hasmask = __ballot(act && qj != 0xFFFF);
        const bool found  = (hasmask != 0ull);
        const int  k      = found ? (int)__builtin_ctzll(hasmask) : L;

        // transition-setting walk: chain[0..k) get b[p][t] = r  (BEFORE round B reads)
        if (lane < k) tr16[2 * vch + t] = (u16)r;

        // ---- round B: gather tr/el of the image states q_j ----
        const int qe  = (act && qj != 0xFFFF) ? qj : 0;
        const u32 trq = tr[qe];
        const u32 elq = el[qe];
        const int prevq = __shfl_up(qj, 1);

        int u_id  = -1;
        int j_end = k;      // lanes [k, j_end) get redirected to clone u
        if (found) {
            const int q     = __builtin_amdgcn_readlane(qj, k);
            const u32 elv_k = (u32)__builtin_amdgcn_readlane((int)elv, k);
            const u32 elq_k = (u32)__builtin_amdgcn_readlane((int)elq, k);
            const int len_p = (int)(elv_k >> 16);
            const int len_q = (int)(elq_k >> 16);
            if (len_p + 1 != len_q) {
                // clone u of q
                u_id = z++;
                const u64 eqm = __ballot(act && qj == q);
                const u64 nq  = (~eqm) >> k;
                const int runlen = nq ? (int)__builtin_ctzll(nq) : (64 - k);
                j_end = k + runlen;
                if (lane >= k && lane < j_end) tr16[2 * vch + t] = (u16)u_id;
                const u32 trq_k = (u32)__builtin_amdgcn_readlane((int)trq, k);
                if (lane == 0) {
                    tr[u_id] = trq_k;                                    // b[u]=b[q] (post-walk)
                    el[u_id] = ((u32)(len_p + 1) << 16) | (elq_k & 0xFFFFu); // len, e[u]=e[q]
                }
            }
        }

        // ---- images, adjacent-dedupe, compaction ----
        const bool part = act && lane >= k;
        const int  img  = (lane < j_end) ? u_id : qj;
        const bool keep = part && (lane == k || lane == j_end ||
                                   (lane > j_end && qj != prevq));
        const u64 keepm = __ballot(keep);
        const int cnt   = __popcll(keepm);
        const int Lnew  = cnt + 2;                       // + r at front, + root at back
        const int pos   = __popcll(keepm & ((1ull << lane) - 1ull));
        const int dest  = keep ? (1 + pos) : 63;         // junk lanes park at 63
        const u32 pushval = (u32)(img & 0xFFFF) | ((elq & 0xFFFFu) << 16); // img | e[q_j]
        const int perm  = __builtin_amdgcn_ds_permute(dest << 2, (int)pushval);
        const int e_m   = (int)(short)((u32)perm >> 16); // pre-update e of new chain entry

        // ---- predictor: first chain state (below top, above root) with e >= 0 ----
        int a = -1;
        const u64 pmask = __ballot(lane >= 1 && lane < Lnew - 1 && e_m >= 0);
        if (pmask) {
            const int m0 = (int)__builtin_ctzll(pmask);
            const int ev = __builtin_amdgcn_readlane(e_m, m0);
            const int j2 = ev + 1;
            const u64 w  = bits[j2 >> 6];
            a = (int)((w >> (j2 & 63)) & 1ull);
        }
        if (lane == 0) y8[i] = (signed char)a;

        // ---- new chain registers ----
        const int vnew = (lane == 0) ? r : ((lane < Lnew - 1) ? (perm & 0xFFFF) : 0);

        // ---- creation + e-update writes ----
        if (lane == 0) {
            tr[r] = 0xFFFFFFFFu;
            el[r] = ((u32)(i + 1) << 16) | (u32)(u16)i;  // len=i+1, e=i (post e-walk)
        }
        if (lane >= 1 && lane < Lnew) el16[2 * vnew] = (u16)i;  // e[v]=i along chain

        vch = vnew;
        L   = Lnew;
        if ((i & 63) == 63) curw = nxtw;
    }
    __syncthreads();

    // ---- phase 3: select + store ----
    const float e0 = emb0[cc];
    const float e1 = emb1[cc];
    float* op = out + (size_t)bb * T_ * C_ + cc;
    for (int tt = lane; tt < T_; tt += 64) {
        int yv = y8[tt];
        op[(size_t)tt * C_] = (yv < 0) ? 0.0f : (yv ? e1 : e0);
    }
}

extern "C" void kernel_launch(void* const* d_in, const int* in_sizes, int n_in,
                              void* d_out, int out_size, void* d_ws, size_t ws_size,
                              hipStream_t stream)
{
    const float* x    = (const float*)d_in[0];
    const float* emb0 = (const float*)d_in[1];
    const float* emb1 = (const float*)d_in[2];
    float* out = (float*)d_out;

    dim3 grid(B_ * C_);
    dim3 block(64);
    rosa_kernel<<<grid, block, 0, stream>>>(x, emb0, emb1, out);
}

// Round 5
// 1073.491 us; speedup vs baseline: 3.7887x; 1.1881x over previous
//
#include <hip/hip_runtime.h>

// ROSA 1-bit layer — wave-parallel suffix automaton, v3.2.
// Chain kept SPARSE one-state-per-lane (lane order = chain order).
// Per step: qj from pipelined tr-gather -> B ds_read_b64 st[q] (the only
// dependent LDS round) -> clone/keep fixups -> issue next tr-gather.
// v3.2 fix: the reference copies b[u]=b[q] AFTER the walk writes b[p][t]=r.
// Our B-gather is pre-walk, so when q aliases a walk-written state ({g} or
// chain[j<k] — e.g. any "..X^m Y Y" pattern makes q==g with a clone), patch
// the stale copy in registers: slot t := r.

#define B_   2
#define T_   2048
#define C_   128
#define MAXS 4100   // max states = 2T+1 = 4097

typedef unsigned int       u32;
typedef unsigned short     u16;
typedef unsigned long long u64;
typedef u16 __attribute__((may_alias)) u16a;
typedef u32 __attribute__((may_alias)) u32a;

__global__ __launch_bounds__(64)
void rosa_kernel(const float* __restrict__ x,
                 const float* __restrict__ emb0,
                 const float* __restrict__ emb1,
                 float* __restrict__ out)
{
    // st[v]: w0 = transitions (lo16 sym0, hi16 sym1; 0xFFFF = none)
    //        w1 = e (lo16, u16) | (len | f<<15) (hi16), f = x[e+1]
    __shared__ u64 st[MAXS];
    __shared__ u64 bits[T_ / 64];
    __shared__ signed char y8[T_];
    __shared__ u32 scratch[64];

    const int blk  = blockIdx.x;
    const int bb   = blk >> 7;
    const int cc   = blk & (C_ - 1);
    const int lane = threadIdx.x;

    // ---- phase 1: cooperative bit packing ----
    const float* xp = x + (size_t)bb * T_ * C_ + cc;
    for (int k = 0; k < T_ / 64; ++k) {
        float v = xp[(size_t)(k * 64 + lane) * C_];
        u64 m = __ballot(v > 0.0f);
        if (lane == 0) bits[k] = m;
    }
    __syncthreads();

    u16a* tr16 = (u16a*)st;   // tr16[4*v + t]
    u32a* st32 = (u32a*)st;   // st32[2*v] = tr word, st32[2*v+1] = e|len|f word

    // ---- step 0 (trivial, scalar) ----
    u64 curw = bits[0];
    {
        const int t0 = (int)(curw & 1ull);
        const int f0 = (int)((curw >> 1) & 1ull);
        if (lane == 0) {
            u32 tr0 = 0xFFFFFFFFu & ~(0xFFFFu << (t0 * 16));
            tr0 |= (1u << (t0 * 16));
            st[0] = ((u64)((u32)((0 | (f0 << 15)) << 16)) << 32) | tr0;         // e=0,len=0
            st[1] = ((u64)((u32)((1 | (f0 << 15)) << 16)) << 32) | 0xFFFFFFFFu; // e=0,len=1
            y8[0] = (signed char)(-1);
        }
    }

    // ---- phase 2: sparse wave-parallel construction ----
    bool act  = (lane == 63);   // root lives at lane 63; middles sparse in [1..62]
    int  vid  = 0;              // state id per lane
    int  vlen = 0;              // len per lane
    int  g    = 1;              // top state (scalar; tr(g) always empty at step start)
    int  z    = 2;
    u64  nxtw = bits[1];
    u32  trv  = st32[2 * vid];  // pipelined A-gather (in-order LDS after lane0's writes)

    for (int i = 1; i < T_; ++i) {
        if ((i & 63) == 0) { curw = nxtw; int w = (i >> 6) + 1; nxtw = (w < T_/64) ? bits[w] : 0ull; }
        const int ii = i & 63;
        const int t  = (int)((curw >> ii) & 1ull);
        const int fb = (ii == 63) ? (int)(nxtw & 1ull) : (int)((curw >> (ii + 1)) & 1ull);
        const int sh = t << 4;

        // qj from pipelined gather
        const int qj = act ? (int)((trv >> sh) & 0xFFFFu) : 0xFFFF;
        const u64 hasmask = __ballot(qj != 0xFFFF);
        const bool found  = hasmask != 0ull;
        const int  k      = found ? (int)__builtin_ctzll(hasmask) : 64;
        const int  ks     = k & 63;

        // B-gather (the one dependent LDS round) + prevq bpermute in parallel
        const int qe  = (qj == 0xFFFF) ? 0 : qj;
        const u64 stq = st[qe];
        const u64 Am  = __ballot(act);
        const u64 below = Am & ((1ull << lane) - 1ull);
        const int pidx  = below ? (63 - __builtin_clzll(below)) : 0;
        const int prevq = __builtin_amdgcn_ds_bpermute(pidx << 2, qj);

        const u32 trq = (u32)(stq & 0xFFFFFFFFu);
        const u32 elq = (u32)(stq >> 32);
        const int lenq = (int)((elq >> 16) & 0x7FFFu);

        const int q      = __builtin_amdgcn_readlane(qj, ks);
        const int lenp   = __builtin_amdgcn_readlane(vlen, ks);
        const int lenq_k = __builtin_amdgcn_readlane(lenq, ks);
        const u32 elq_k  = (u32)__builtin_amdgcn_readlane((int)elq, ks);

        const bool clone = found && (lenp + 1 != lenq_k);
        const int r  = z;
        const int u_ = z + 1;
        z += clone ? 2 : 1;

        // alias detect: q among this step's walk-written states ({g} U chain[<k])
        const u64 aliasm = __ballot(act && lane < k && vid == q);
        const bool qstale = (q == g) || (aliasm != 0ull);

        // redirect run [k, b0): active lanes with qj == q, below first mismatch
        const u64 aboveK = ~((2ull << ks) - 1ull);   // lanes > k (k=63 -> 0)
        const u64 eqm  = __ballot(qj == q);
        const u64 badm = Am & ~eqm & aboveK;
        const int b0   = badm ? (int)__builtin_ctzll(badm) : 64;
        const bool redir = clone && act && lane >= k && lane < b0 && (qj == q);

        // keep: images of chain[k..], adjacent-dedupe
        const bool keep = act && lane >= k && (lane == k || qj != prevq);
        const int id_cand  = (clone && lane == k) ? u_ : qj;
        const int len_cand = (clone && lane == k) ? (lenp + 1) : lenq;
        const u64 keepm = __ballot(keep);

        // ---- tr writes ----
        if (act && lane < k) tr16[4 * vid + t] = (u16)r;   // walk writes (incl. !found case)
        if (lane == 0)       tr16[4 * g + t]   = (u16)r;   // top write (tr(g) empty pre-step)
        if (redir)           tr16[4 * vid + t] = (u16)u_;  // clone redirects
        if (clone && lane == 0) {
            u32 trqk = (u32)__builtin_amdgcn_readlane((int)trq, ks);
            if (qstale) trqk = (trqk & ~(0xFFFFu << sh)) | ((u32)r << sh);  // post-walk copy
            const u32 w1u = (u32)(u16)i | ((u32)((lenp + 1) | (fb << 15)) << 16); // e=i post-walk
            st[u_] = ((u64)w1u << 32) | trqk;
        }

        // ---- e/f updates + top create + predictor output ----
        const u32 efv = (u32)(u16)i | ((u32)(len_cand | (fb << 15)) << 16);
        if (keep) st32[2 * id_cand + 1] = efv;
        if (lane == 0) {
            const u32 w1r = (u32)(u16)i | ((u32)((i + 1) | (fb << 15)) << 16);
            st[r] = ((u64)w1r << 32) | 0xFFFFFFFFu;                       // create top r
            st32[1] = (u32)(u16)i | ((u32)(0 | (fb << 15)) << 16);        // root e/f
            const int a = found ? (int)((elq_k >> 31) & 1u) : -1;         // f-bit of q (pre-update)
            y8[i] = (signed char)a;
        }

        // ---- new sparse chain ----
        const bool k63 = (keepm >> 63) & 1ull;                 // root's image kept?
        const u64  kmid = keepm & 0x7FFFFFFFFFFFFFFFull;
        const int  P = kmid ? (63 - __builtin_clzll(kmid)) : 0;
        const int  newpos = P + 1;
        const bool recomp = k63 && (newpos >= 63);

        bool actn = (keep && lane < 63) || (lane == 63);
        int  idn  = (keep && lane < 63) ? id_cand : 0;         // lane 63 -> root(0)
        int  lenn = (keep && lane < 63) ? len_cand : 0;

        if (k63 && !recomp) {                                  // move root image to newpos
            const int sId  = __builtin_amdgcn_readlane(id_cand, 63);   // wave-uniform
            const int sLen = __builtin_amdgcn_readlane(len_cand, 63);  // wave-uniform
            if (lane == newpos) { idn = sId; lenn = sLen; actn = true; }
        }
        if (recomp) {                                          // rare: dense repack via scratch
            const int dest = 1 + (int)__builtin_popcountll(keepm & ((1ull << lane) - 1ull));
            if (keep) scratch[dest] = (u32)id_cand | ((u32)len_cand << 16);
            const int cnt = (int)__builtin_popcountll(keepm);
            const u32 sc = scratch[lane];
            const bool inr = (lane >= 1 && lane <= cnt);
            actn = inr || (lane == 63);
            idn  = (lane == 63) ? 0 : (inr ? (int)(sc & 0xFFFFu) : 0);
            lenn = (lane == 63) ? 0 : (inr ? (int)(sc >> 16) : 0);
        }

        act = actn; vid = idn; vlen = lenn; g = r;
        trv = st32[2 * vid];                                   // pipelined A for next step
    }
    __syncthreads();

    // ---- phase 3: select + store ----
    const float e0 = emb0[cc];
    const float e1 = emb1[cc];
    float* op = out + (size_t)bb * T_ * C_ + cc;
    for (int tt = lane; tt < T_; tt += 64) {
        int yv = y8[tt];
        op[(size_t)tt * C_] = (yv < 0) ? 0.0f : (yv ? e1 : e0);
    }
}

extern "C" void kernel_launch(void* const* d_in, const int* in_sizes, int n_in,
                              void* d_out, int out_size, void* d_ws, size_t ws_size,
                              hipStream_t stream)
{
    const float* x    = (const float*)d_in[0];
    const float* emb0 = (const float*)d_in[1];
    const float* emb1 = (const float*)d_in[2];
    float* out = (float*)d_out;

    dim3 grid(B_ * C_);
    dim3 block(64);
    rosa_kernel<<<grid, block, 0, stream>>>(x, emb0, emb1, out);
}